// Round 10
// baseline (196.127 us; speedup 1.0000x reference)
//
#include <hip/hip_runtime.h>
#include <hip/hip_bf16.h>

// B=2, S=2048, D=1024, H=16, dk=64. INPUTS FP32, OUTPUT FP32. M = 4096 rows.
// ROUND 28: BARRIER-FREE REG-STREAMING GEMMS. The LDS-staged 128^2 structure
// saturated at ~60us (r22 2-barrier == r26 ring-3: the stage->vmcnt->barrier
// convoy is the floor, ~4500cy/step for 240cy of MFMA). Since we control all
// producer layouts, A and B are now stored in MFMA FRAGMENT-MAJOR chunks
// (16 rows x 32 k-cols, lane-contiguous 16B) and each wave loads fragments
// global->VGPR directly: perfectly coalesced, ZERO LDS staging, ZERO barriers
// (same proven structure as the attn K/V loop since r21). Waves free-run.
//   - convs emit fragment-major bf16 (x, Wqkv, Wo)
//   - QKV gemm: reg-streaming; validated r22 epilogue (Ct+rope+QKV layouts)
//   - attn: unchanged math; output stored fragment-major (feeds proj)
//   - proj: 1-wave 64x64 blocks (grid 1024), reg-streaming, LDS-transposed
//     coalesced fp32 epilogue

typedef __bf16 bf16x8 __attribute__((ext_vector_type(8)));
typedef float f32x4 __attribute__((ext_vector_type(4)));

#define LOG2E 1.4426950408889634f

__device__ __forceinline__ ushort f2bf(float f) {
  __hip_bfloat16 h = __float2bfloat16(f);
  return __builtin_bit_cast(ushort, h);
}

__device__ __forceinline__ uint pack2(float a, float b) {
  return (uint)f2bf(a) | ((uint)f2bf(b) << 16);
}

// truncating bf16x2 pack in one v_perm_b32
__device__ __forceinline__ uint pack2t(float a, float b) {
  return __builtin_amdgcn_perm(__builtin_bit_cast(uint, b),
                               __builtin_bit_cast(uint, a), 0x07060302u);
}

// single-instruction 2^x (quarter-rate trans pipe)
__device__ __forceinline__ float fexp2(float x) {
#if __has_builtin(__builtin_amdgcn_exp2f)
  return __builtin_amdgcn_exp2f(x);
#else
  float r;
  asm volatile("v_exp_f32 %0, %1\n\ts_nop 0" : "=v"(r) : "v"(x));
  return r;
#endif
}

#define CBAR() __asm__ __volatile__("" ::: "memory")

// -------------------------------------------- fp32 -> bf16 FRAGMENT-MAJOR
// src row-major [R x 1024] fp32 -> dst fragment chunks: chunk (r16, k32) is
// 512 ushorts; elem ((quad*16 + rr)*8 + j) = src[r16*16+rr][k32*32+quad*8+j].
// Thread i handles src row i>>7, cols (i&127)*8 .. +7 -> ONE 16B chunk write.
__device__ __forceinline__ void conv_frag_one(const float* __restrict__ src,
                                              ushort* __restrict__ dst, int i) {
  int row = i >> 7, cc = i & 127;  // cc = col/8
  int r16 = row >> 4, rr = row & 15;
  int k32 = cc >> 2, quad = cc & 3;
  const float4* s = (const float4*)src + (long)i * 2;
  float4 a = s[0], b = s[1];
  uint4 pk = {pack2(a.x, a.y), pack2(a.z, a.w), pack2(b.x, b.y), pack2(b.z, b.w)};
  *(uint4*)&dst[((long)r16 * 32 + k32) * 512 + (quad * 16 + rr) * 8] = pk;
}

__global__ __launch_bounds__(256) void conv_frag(const float* __restrict__ src,
                                                 ushort* __restrict__ dst,
                                                 int n8) {
  int i = blockIdx.x * 256 + threadIdx.x;
  if (i >= n8) return;
  conv_frag_one(src, dst, i);
}

// two-segment (x -> xh, Wqkv -> wqkvh) in one dispatch
__global__ __launch_bounds__(256) void conv_frag2(
    const float* __restrict__ s0, ushort* __restrict__ d0, int n0,
    const float* __restrict__ s1, ushort* __restrict__ d1, int n1) {
  int i = blockIdx.x * 256 + threadIdx.x;
  if (i < n0) {
    conv_frag_one(s0, d0, i);
  } else {
    i -= n0;
    if (i >= n1) return;
    conv_frag_one(s1, d1, i);
  }
}

// ---------------------------------------------------------- QKV GEMM (NT)
// A [4096 x 1024] frag-major bf16, B [3072 x 1024] frag-major bf16 (B^T GEMM).
// 128^2 tiles, 4 waves, reg-streaming (no staging LDS, no barriers in loop).
// Epilogue (validated r22): Q row-major (+rope), K/V fragment-major.
__global__ __launch_bounds__(256) void gemm_bt(
    const ushort* __restrict__ A, const ushort* __restrict__ B, int nbn,
    ushort* __restrict__ qb, ushort* __restrict__ kb, ushort* __restrict__ vb) {
  __shared__ __align__(16) ushort SMEM[17408];  // epilogue Ct 128x136 only
  const int tid = threadIdx.x;
  const int w = tid >> 6, lane = tid & 63, quad = lane >> 4, lc = lane & 15;
  const int bid = blockIdx.x;
  const int bm = bid / nbn, bn = bid % nbn;
  const int wm = (w & 1) * 64, wn = (w >> 1) * 64;

  f32x4 acc[4][4] = {};

  // fragment bases: chunk (r16, k32) at elem (r16*32 + k32)*512 + lane*8;
  // per-wave A rows start at r16 = bm*8 + (w&1)*4, B at bn*8 + (w>>1)*4.
  const ushort* Ap = A + (long)(bm * 8 + (w & 1) * 4) * 16384 + lane * 8;
  const ushort* Bp = B + (long)(bn * 8 + (w >> 1) * 4) * 16384 + lane * 8;

#define GLD(AF, BF, K32)                                                       \
  {                                                                            \
    for (int t = 0; t < 4; ++t)                                                \
      AF[t] = *(const bf16x8*)&Ap[(long)t * 16384 + (K32) * 512];              \
    for (int t = 0; t < 4; ++t)                                                \
      BF[t] = *(const bf16x8*)&Bp[(long)t * 16384 + (K32) * 512];              \
  }
#define MM(AF, BF)                                                             \
  for (int rt = 0; rt < 4; ++rt)                                               \
    for (int ct = 0; ct < 4; ++ct)                                             \
      acc[rt][ct] = __builtin_amdgcn_mfma_f32_16x16x32_bf16(                   \
          AF[rt], BF[ct], acc[rt][ct], 0, 0, 0);

  bf16x8 a0[4], b0[4], a1[4], b1[4];
  GLD(a0, b0, 0);
  for (int k = 0; k < 32; k += 2) {
    GLD(a1, b1, k + 1);
    MM(a0, b0);
    int kn = (k + 2 < 32) ? k + 2 : 31;  // clamp: last reload redundant/unused
    GLD(a0, b0, kn);
    MM(a1, b1);
  }
#undef GLD
#undef MM

  {
    const int e0 = bn * 128;
    const int g = e0 >> 10;
    const int h0 = (e0 & 1023) >> 6;  // tile covers heads h0, h0+1
    ushort* Ct = SMEM;                // 128 x 136 staging
    __syncthreads();

    if (g == 2) {
      // V: transposed staging T[col][row] -> uint2 writes (4 consecutive rows)
      for (int rt = 0; rt < 4; ++rt)
        for (int ct = 0; ct < 4; ++ct) {
          int col = wn + ct * 16 + lc;
          int r0 = wm + rt * 16 + quad * 4;
          uint2 pk = {pack2(acc[rt][ct][0], acc[rt][ct][1]),
                      pack2(acc[rt][ct][2], acc[rt][ct][3])};
          *(uint2*)&Ct[col * 136 + r0] = pk;
        }
    } else {
      // Q/K: rope + row-major staging
      const float qs = (g == 0) ? 0.125f * LOG2E : 1.0f;
      const float ang = powf(1e-4f, (float)lc * (1.0f / 15.0f));
      for (int rt = 0; rt < 4; ++rt)
        for (int r = 0; r < 4; ++r) {
          int row = wm + rt * 16 + quad * 4 + r;
          int srow = (bm * 128 + row) & 2047;
          float theta = (float)srow * ang;
          float sn, c;
          sincosf(theta, &sn, &c);
          float x1 = acc[rt][0][r], x2 = acc[rt][2][r];
          acc[rt][0][r] = x1 * c - x2 * sn;
          acc[rt][2][r] = x1 * sn + x2 * c;
          for (int ct = 0; ct < 4; ++ct)
            Ct[row * 136 + wn + ct * 16 + lc] = f2bf(acc[rt][ct][r] * qs);
        }
    }
    __syncthreads();

    if (g == 0) {
      for (int i = 0; i < 8; ++i) {
        int u = i * 256 + tid;
        int row = u >> 4, c8 = u & 15;
        int m = bm * 128 + row;
        int srow = m & 2047, b = m >> 11;
        uint4 vv = *(const uint4*)&Ct[row * 136 + c8 * 8];
        *(uint4*)&qb[(((long)(b * 16 + h0 + (c8 >> 3))) * 2048 + srow) * 64 +
                     (c8 & 7) * 8] = vv;
      }
    } else if (g == 1) {
      for (int i = 0; i < 8; ++i) {
        int u = i * 256 + tid;
        int head = u >> 10, off = u & 1023;
        int jrel = off >> 9, kc = (off >> 8) & 1, t = (off >> 6) & 3;
        int quadK = (off >> 4) & 3, lcA = off & 15;
        int srl = jrel * 64 + t * 16 + lcA;
        uint4 vv = *(const uint4*)&Ct[srl * 136 + head * 64 + kc * 32 + quadK * 8];
        int m = bm * 128 + srl;
        int srow = m & 2047, b = m >> 11;
        int bh = b * 16 + h0 + head;
        int chunk = (srow >> 6) * 8 + kc * 4 + t;
        *(uint4*)&kb[(long)bh * 131072 + chunk * 512 + (quadK * 16 + lcA) * 8] = vv;
      }
    } else {
      for (int i = 0; i < 8; ++i) {
        int u = i * 256 + tid;
        int head = u >> 10, off = u & 1023;
        int jrel = off >> 9, kcV = (off >> 8) & 1, mt = (off >> 6) & 3;
        int quadV = (off >> 4) & 3, lcA = off & 15;
        int srl = jrel * 64 + kcV * 32 + quadV * 8;
        int d = mt * 16 + lcA;
        uint4 vv = *(const uint4*)&Ct[(head * 64 + d) * 136 + srl];
        int m = bm * 128 + srl;
        int srow = m & 2047, b = m >> 11;
        int bh = b * 16 + h0 + head;
        int chunk = (srow >> 6) * 8 + kcV * 4 + mt;
        *(uint4*)&vb[(long)bh * 131072 + chunk * 512 + (quadV * 16 + lcA) * 8] = vv;
      }
    }
  }
}

// ------------------------------------------------- projection GEMM (NT)
// C[4096 x 1024] fp32 = AO[4096 x 1024] frag * Wo[1024 x 1024]^T frag.
// ONE WAVE PER BLOCK, 64x64 tile, grid 64x16 = 1024 blocks, reg-streaming,
// LDS-transposed coalesced fp32 epilogue (4 rows x 256B per store pass).
__global__ __launch_bounds__(64) void gemm_proj(
    const ushort* __restrict__ A, const ushort* __restrict__ B,
    float* __restrict__ Cout) {
  __shared__ __align__(16) float T[64 * 68];
  const int lane = threadIdx.x, quad = lane >> 4, lc = lane & 15;
  const int bid = blockIdx.x;
  const int bm = bid >> 4, bn = bid & 15;

  f32x4 acc[4][4] = {};

  const ushort* Ap = A + (long)(bm * 4) * 16384 + lane * 8;
  const ushort* Bp = B + (long)(bn * 4) * 16384 + lane * 8;

#define GLD(AF, BF, K32)                                                       \
  {                                                                            \
    for (int t = 0; t < 4; ++t)                                                \
      AF[t] = *(const bf16x8*)&Ap[(long)t * 16384 + (K32) * 512];              \
    for (int t = 0; t < 4; ++t)                                                \
      BF[t] = *(const bf16x8*)&Bp[(long)t * 16384 + (K32) * 512];              \
  }
#define MM(AF, BF)                                                             \
  for (int rt = 0; rt < 4; ++rt)                                               \
    for (int ct = 0; ct < 4; ++ct)                                             \
      acc[rt][ct] = __builtin_amdgcn_mfma_f32_16x16x32_bf16(                   \
          AF[rt], BF[ct], acc[rt][ct], 0, 0, 0);

  bf16x8 a0[4], b0[4], a1[4], b1[4];
  GLD(a0, b0, 0);
  for (int k = 0; k < 32; k += 2) {
    GLD(a1, b1, k + 1);
    MM(a0, b0);
    int kn = (k + 2 < 32) ? k + 2 : 31;
    GLD(a0, b0, kn);
    MM(a1, b1);
  }
#undef GLD
#undef MM

  // transpose via LDS (single wave: DS pipe is in-order, CBAR suffices)
  for (int rt = 0; rt < 4; ++rt)
    for (int ct = 0; ct < 4; ++ct)
      for (int r = 0; r < 4; ++r)
        T[(rt * 16 + quad * 4 + r) * 68 + ct * 16 + lc] = acc[rt][ct][r];
  CBAR();
  for (int p = 0; p < 16; ++p) {
    int row = p * 4 + quad;  // 4 rows per pass, 16 lanes x 16B = 256B/row
    float4 v = *(const float4*)&T[row * 68 + lc * 4];
    *(float4*)&Cout[(long)(bm * 64 + row) * 1024 + bn * 64 + lc * 4] = v;
  }
}

// ---------------------------------------------------------------- attention
// ONE WAVE PER BLOCK, 32 q-rows. Fragment-major coalesced K/V loads (r21),
// fixed-max softmax (bias dropped), 2x-unrolled A/B register ping-pong,
// setprio around MFMA clusters. Output stored FRAGMENT-MAJOR (feeds proj).
__global__ __launch_bounds__(64) void attn_kernel(
    const ushort* __restrict__ qb, const ushort* __restrict__ kb,
    const ushort* __restrict__ vt, ushort* __restrict__ out) {
  __shared__ __align__(16) ushort Psw2[2][32 * 64];
  const int lane = threadIdx.x;
  const int quad = lane >> 4, lc = lane & 15, l7 = lc & 7;
  const int bid = blockIdx.x;                   // 0..2047
  const int s = 63 - (bid >> 5);                // strip, big-work first
  const int bh = bid & 31;
  const int bidx = bh >> 4, h = bh & 15;
  const int qtbase = s * 32;

  bf16x8 qf[2][2];
  for (int kc = 0; kc < 2; ++kc)
    for (int q2 = 0; q2 < 2; ++q2)
      qf[kc][q2] = *(const bf16x8*)&qb[((long)bh * 2048 + qtbase + q2 * 16 + lc) * 64 +
                                       kc * 32 + quad * 8];

  f32x4 oacc[4][2] = {};
  float l_lane[2] = {0.0f, 0.0f};

  const ushort* K = kb + (long)bh * 131072;
  const ushort* Vt = vt + (long)bh * 131072;
  const int jmax = s >> 1;
  const int rowoff = (s & 1) * 32;
  const int lane8 = lane * 8;

#define LOADTILE(KF, VF, JT)                                                   \
  {                                                                            \
    const ushort* Kp_ = K + (JT) * 4096 + lane8;                               \
    const ushort* Vp_ = Vt + (JT) * 4096 + lane8;                              \
    for (int kc = 0; kc < 2; ++kc)                                             \
      for (int t = 0; t < 4; ++t) {                                            \
        KF[kc][t] = *(const bf16x8*)&Kp_[(kc * 4 + t) * 512];                  \
        VF[kc][t] = *(const bf16x8*)&Vp_[(kc * 4 + t) * 512];                  \
      }                                                                        \
  }

#define COMPUTE(KF, VF, J, PAR)                                                \
  {                                                                            \
    f32x4 sacc[4][2] = {};                                                     \
    __builtin_amdgcn_s_setprio(1);                                             \
    for (int kc = 0; kc < 2; ++kc)                                             \
      for (int kt = 0; kt < 4; ++kt)                                           \
        for (int q2 = 0; q2 < 2; ++q2)                                         \
          sacc[kt][q2] = __builtin_amdgcn_mfma_f32_16x16x32_bf16(              \
              KF[kc][kt], qf[kc][q2], sacc[kt][q2], 0, 0, 0);                  \
    __builtin_amdgcn_s_setprio(0);                                             \
    if ((J) == jmax) { /* causal partial tile */                               \
      for (int kt = 0; kt < 4; ++kt)                                           \
        for (int q2 = 0; q2 < 2; ++q2) {                                       \
          int rowrel = rowoff + q2 * 16 + lc;                                  \
          for (int r = 0; r < 4; ++r)                                          \
            if (kt * 16 + quad * 4 + r > rowrel) sacc[kt][q2][r] = -1.0e30f;   \
        }                                                                      \
    }                                                                          \
    ushort* Psw = Psw2[PAR];                                                   \
    for (int q2 = 0; q2 < 2; ++q2) {                                           \
      float p[4][4];                                                           \
      float rs = 0.0f;                                                         \
      for (int kt = 0; kt < 4; ++kt)                                           \
        for (int r = 0; r < 4; ++r) {                                          \
          p[kt][r] = fexp2(sacc[kt][q2][r]);                                   \
          rs += p[kt][r];                                                      \
        }                                                                      \
      l_lane[q2] += rs;                                                        \
      for (int kt = 0; kt < 4; ++kt) {                                         \
        uint2 pk = {pack2t(p[kt][0], p[kt][1]), pack2t(p[kt][2], p[kt][3])};   \
        *(uint2*)&Psw[(q2 * 16 + lc) * 64 +                                    \
                      (((kt * 2 + (quad >> 1)) ^ l7) << 3) +                   \
                      ((quad & 1) << 2)] = pk;                                 \
      }                                                                        \
    }                                                                          \
    CBAR(); /* compiler-only: P writes before P reads (HW DS in-order) */      \
    __builtin_amdgcn_s_setprio(1);                                             \
    for (int kc = 0; kc < 2; ++kc) {                                           \
      bf16x8 pf[2];                                                            \
      for (int q2 = 0; q2 < 2; ++q2)                                           \
        pf[q2] = *(const bf16x8*)&Psw[(q2 * 16 + lc) * 64 +                    \
                                      (((kc * 4 + quad) ^ l7) << 3)];          \
      for (int mt = 0; mt < 4; ++mt)                                           \
        for (int q2 = 0; q2 < 2; ++q2)                                         \
          oacc[mt][q2] = __builtin_amdgcn_mfma_f32_16x16x32_bf16(              \
              VF[kc][mt], pf[q2], oacc[mt][q2], 0, 0, 0);                      \
    }                                                                          \
    __builtin_amdgcn_s_setprio(0);                                             \
  }

  // 2x-unrolled software pipeline with A/B register ping-pong.
  bf16x8 kA[2][4], vA[2][4], kB[2][4], vB[2][4];
  LOADTILE(kA, vA, 0);
  int j = 0;
  while (true) {
    int jn = (j < jmax) ? j + 1 : j;
    LOADTILE(kB, vB, jn);
    COMPUTE(kA, vA, j, 0);
    if (j >= jmax) break;
    ++j;
    int jn2 = (j < jmax) ? j + 1 : j;
    LOADTILE(kA, vA, jn2);
    COMPUTE(kB, vB, j, 1);
    if (j >= jmax) break;
    ++j;
  }
#undef LOADTILE
#undef COMPUTE

  // epilogue: reduce l across quads, normalize, store via LDS
  float l_[2];
  for (int q2 = 0; q2 < 2; ++q2) {
    float rs = l_lane[q2];
    rs += __shfl_xor(rs, 16, 64);
    rs += __shfl_xor(rs, 32, 64);
    l_[q2] = rs;
  }
  ushort* Psw = Psw2[0];
  CBAR();
  for (int q2 = 0; q2 < 2; ++q2) {
    float linv = 1.0f / l_[q2];
    for (int mt = 0; mt < 4; ++mt) {
      uint2 pk = {pack2(oacc[mt][q2][0] * linv, oacc[mt][q2][1] * linv),
                  pack2(oacc[mt][q2][2] * linv, oacc[mt][q2][3] * linv)};
      *(uint2*)&Psw[(q2 * 16 + lc) * 64 + (((mt * 2 + (quad >> 1)) ^ l7) << 3) +
                    ((quad & 1) << 2)] = pk;
    }
  }
  CBAR();
  {
    // store FRAGMENT-MAJOR: AO[m][col] -> chunk (m>>4, col>>5), elem
    // (((col>>3)&3)*16 + (m&15))*8. col = h*64 + c8*8.
    int r2 = lane >> 1;
    long m = (long)bidx * 2048 + qtbase + r2;
    int m4 = (int)(m >> 4), rr = (int)(m & 15);
    for (int c = 0; c < 4; ++c) {
      int c8 = (lane & 1) * 4 + c;
      uint4 vv = *(const uint4*)&Psw[r2 * 64 + ((c8 ^ (r2 & 7)) << 3)];
      *(uint4*)&out[((long)m4 * 32 + h * 2 + (c8 >> 2)) * 512 +
                    ((c8 & 3) * 16 + rr) * 8] = vv;
    }
  }
}

extern "C" void kernel_launch(void* const* d_in, const int* in_sizes, int n_in,
                              void* d_out, int out_size, void* d_ws, size_t ws_size,
                              hipStream_t stream) {
  const float* x = nullptr;     // 4194304 elems
  const float* Wqkv = nullptr;  // 3145728 elems
  const float* Wo = nullptr;    // 1048576 elems
  for (int i = 0; i < n_in; ++i) {
    if (in_sizes[i] == 4194304) x = (const float*)d_in[i];
    else if (in_sizes[i] == 3145728) Wqkv = (const float*)d_in[i];
    else if (in_sizes[i] == 1048576) Wo = (const float*)d_in[i];
  }
  float* out = (float*)d_out;  // [4096,1024] fp32 (16 MiB)

  // Workspace (32 MiB) timeline:
  //  [0,8)   qbuf (Q row-major)          -> later Wo bf16 frag (woh)
  //  [8,16)  kbuf (K fragment-major)
  //  [16,24) vbuf (V fragment-major)
  //  [24,32) scratch: Wqkv bf16 frag -> attn output frag (ao) after gemm1
  ushort* qbuf = (ushort*)d_ws;
  ushort* kbuf = qbuf + 4194304;
  ushort* vbuf = kbuf + 4194304;
  ushort* scr4 = vbuf + 4194304;
  ushort* wqkvh = scr4;                // Wqkv bf16 frag [24..30)
  ushort* ao   = scr4;                 // attn out frag (after gemm1 done with B)
  ushort* woh  = qbuf;                 // Wo bf16 frag (after attn done with Q)
  ushort* xh   = (ushort*)d_out;       // x bf16 frag in d_out scratch

  conv_frag2<<<3584, 256, 0, stream>>>(x, xh, 524288, Wqkv, wqkvh, 393216);
  gemm_bt<<<768, 256, 0, stream>>>(xh, wqkvh, 24, qbuf, kbuf, vbuf);
  attn_kernel<<<2048, 64, 0, stream>>>(qbuf, kbuf, vbuf, ao);
  conv_frag<<<512, 256, 0, stream>>>(Wo, woh, 131072);
  gemm_proj<<<1024, 64, 0, stream>>>(ao, woh, out);
}

// Round 11
// 188.473 us; speedup vs baseline: 1.0406x; 1.0406x over previous
//
#include <hip/hip_runtime.h>
#include <hip/hip_bf16.h>

// B=2, S=2048, D=1024, H=16, dk=64. INPUTS FP32, OUTPUT FP32. M = 4096 rows.
// ROUND 29: XCD-AWARE REGION SWIZZLE (T1) + FULLY-COALESCED FRAG CONV.
// r28 invariant (~58us for every QKV structure) diagnosed as L2-miss-path BW:
// bid%nbn mapping gives each XCD a ~14MB working set vs 4MB private L2 ->
// most fragment loads miss to L3/fabric (13.2 TB/s sustained). Now XCD x
// (blocks with bid&7==x) owns a 2D region:
//   QKV:  bm in [(x>>1)*8,+8), bn in [(x&1)*12,+12)  -> 2MB A + 3MB B per XCD
//   proj: bm in [x*8,+8), bn all 16                  -> 1MB A + 2MB B per XCD
// Conv rewritten: per-thread 8 consecutive fp32 reads (16 full lines/wave) ->
// 16B lane-contiguous frag writes (1KB/wave). Zero LDS, both sides coalesced
// (r28's frag conv had 4x write-sector inflation).
// attn unchanged (K/V already XCD-local by bh≡bid mod 8: 4 bh x 512KB = 2MB).

typedef __bf16 bf16x8 __attribute__((ext_vector_type(8)));
typedef float f32x4 __attribute__((ext_vector_type(4)));

#define LOG2E 1.4426950408889634f

__device__ __forceinline__ ushort f2bf(float f) {
  __hip_bfloat16 h = __float2bfloat16(f);
  return __builtin_bit_cast(ushort, h);
}

__device__ __forceinline__ uint pack2(float a, float b) {
  return (uint)f2bf(a) | ((uint)f2bf(b) << 16);
}

// truncating bf16x2 pack in one v_perm_b32
__device__ __forceinline__ uint pack2t(float a, float b) {
  return __builtin_amdgcn_perm(__builtin_bit_cast(uint, b),
                               __builtin_bit_cast(uint, a), 0x07060302u);
}

// single-instruction 2^x (quarter-rate trans pipe)
__device__ __forceinline__ float fexp2(float x) {
#if __has_builtin(__builtin_amdgcn_exp2f)
  return __builtin_amdgcn_exp2f(x);
#else
  float r;
  asm volatile("v_exp_f32 %0, %1\n\ts_nop 0" : "=v"(r) : "v"(x));
  return r;
#endif
}

#define CBAR() __asm__ __volatile__("" ::: "memory")

// -------------------------------------------- fp32 -> bf16 FRAGMENT-MAJOR
// dst chunk (r16, k32) is 512 ushorts; elem (quad*16+rr)*8+j =
// src[r16*16+rr][k32*32+quad*8+j]. Block b: r16 = b>>3, kc = b&7 (k32 =
// kc*4 + c). Thread t: c = t>>6, lane = t&63 -> reads 8 consecutive fp32
// (wave: 16 rows x 128B full lines), writes 16B lane-contiguous (1KB/wave).
__device__ __forceinline__ void conv_frag_one(const float* __restrict__ src,
                                              ushort* __restrict__ dst, int b,
                                              int t) {
  int r16 = b >> 3, kc = b & 7;
  int c = t >> 6, lane = t & 63, quad = lane >> 4, rr = lane & 15;
  const float* s =
      src + ((long)(r16 * 16 + rr)) * 1024 + kc * 128 + c * 32 + quad * 8;
  float4 a = *(const float4*)s;
  float4 bb = *(const float4*)(s + 4);
  uint4 pk = {pack2(a.x, a.y), pack2(a.z, a.w), pack2(bb.x, bb.y),
              pack2(bb.z, bb.w)};
  *(uint4*)&dst[((long)(r16 * 32 + kc * 4 + c)) * 512 + lane * 8] = pk;
}

__global__ __launch_bounds__(256) void conv_frag(const float* __restrict__ src,
                                                 ushort* __restrict__ dst) {
  conv_frag_one(src, dst, blockIdx.x, threadIdx.x);
}

// two-segment (x -> xh [nb0 blocks], Wqkv -> wqkvh) in one dispatch
__global__ __launch_bounds__(256) void conv_frag2(
    const float* __restrict__ s0, ushort* __restrict__ d0, int nb0,
    const float* __restrict__ s1, ushort* __restrict__ d1) {
  int b = blockIdx.x;
  if (b < nb0)
    conv_frag_one(s0, d0, b, threadIdx.x);
  else
    conv_frag_one(s1, d1, b - nb0, threadIdx.x);
}

// ---------------------------------------------------------- QKV GEMM (NT)
// A [4096 x 1024] frag-major bf16, B [3072 x 1024] frag-major bf16 (B^T GEMM).
// 128^2 tiles, 4 waves, reg-streaming, XCD region swizzle (8x12 per XCD).
// Epilogue (validated r22): Q row-major (+rope), K/V fragment-major.
__global__ __launch_bounds__(256) void gemm_bt(
    const ushort* __restrict__ A, const ushort* __restrict__ B,
    ushort* __restrict__ qb, ushort* __restrict__ kb, ushort* __restrict__ vb) {
  __shared__ __align__(16) ushort SMEM[17408];  // epilogue Ct 128x136 only
  const int tid = threadIdx.x;
  const int w = tid >> 6, lane = tid & 63, quad = lane >> 4, lc = lane & 15;
  const int bid = blockIdx.x;  // 768 = 8 XCD-regions x 96
  const int r = bid >> 3;
  const int bm = ((bid & 7) >> 1) * 8 + r / 12;   // bm region: 8 rows
  const int bn = (bid & 1) * 12 + r % 12;         // bn region: 12 cols
  const int wm = (w & 1) * 64, wn = (w >> 1) * 64;

  f32x4 acc[4][4] = {};

  // fragment bases: chunk (r16, k32) at elem (r16*32 + k32)*512 + lane*8
  const ushort* Ap = A + (long)(bm * 8 + (w & 1) * 4) * 16384 + lane * 8;
  const ushort* Bp = B + (long)(bn * 8 + (w >> 1) * 4) * 16384 + lane * 8;

#define GLD(AF, BF, K32)                                                       \
  {                                                                            \
    for (int t = 0; t < 4; ++t)                                                \
      AF[t] = *(const bf16x8*)&Ap[(long)t * 16384 + (K32) * 512];              \
    for (int t = 0; t < 4; ++t)                                                \
      BF[t] = *(const bf16x8*)&Bp[(long)t * 16384 + (K32) * 512];              \
  }
#define MM(AF, BF)                                                             \
  for (int rt = 0; rt < 4; ++rt)                                               \
    for (int ct = 0; ct < 4; ++ct)                                             \
      acc[rt][ct] = __builtin_amdgcn_mfma_f32_16x16x32_bf16(                   \
          AF[rt], BF[ct], acc[rt][ct], 0, 0, 0);

  bf16x8 a0[4], b0[4], a1[4], b1[4];
  GLD(a0, b0, 0);
  for (int k = 0; k < 32; k += 2) {
    GLD(a1, b1, k + 1);
    MM(a0, b0);
    int kn = (k + 2 < 32) ? k + 2 : 31;  // clamp: last reload redundant/unused
    GLD(a0, b0, kn);
    MM(a1, b1);
  }
#undef GLD
#undef MM

  {
    const int e0 = bn * 128;
    const int g = e0 >> 10;
    const int h0 = (e0 & 1023) >> 6;  // tile covers heads h0, h0+1
    ushort* Ct = SMEM;                // 128 x 136 staging
    __syncthreads();

    if (g == 2) {
      // V: transposed staging T[col][row] -> uint2 writes (4 consecutive rows)
      for (int rt = 0; rt < 4; ++rt)
        for (int ct = 0; ct < 4; ++ct) {
          int col = wn + ct * 16 + lc;
          int r0 = wm + rt * 16 + quad * 4;
          uint2 pk = {pack2(acc[rt][ct][0], acc[rt][ct][1]),
                      pack2(acc[rt][ct][2], acc[rt][ct][3])};
          *(uint2*)&Ct[col * 136 + r0] = pk;
        }
    } else {
      // Q/K: rope + row-major staging
      const float qs = (g == 0) ? 0.125f * LOG2E : 1.0f;
      const float ang = powf(1e-4f, (float)lc * (1.0f / 15.0f));
      for (int rt = 0; rt < 4; ++rt)
        for (int r2 = 0; r2 < 4; ++r2) {
          int row = wm + rt * 16 + quad * 4 + r2;
          int srow = (bm * 128 + row) & 2047;
          float theta = (float)srow * ang;
          float sn, c;
          sincosf(theta, &sn, &c);
          float x1 = acc[rt][0][r2], x2 = acc[rt][2][r2];
          acc[rt][0][r2] = x1 * c - x2 * sn;
          acc[rt][2][r2] = x1 * sn + x2 * c;
          for (int ct = 0; ct < 4; ++ct)
            Ct[row * 136 + wn + ct * 16 + lc] = f2bf(acc[rt][ct][r2] * qs);
        }
    }
    __syncthreads();

    if (g == 0) {
      for (int i = 0; i < 8; ++i) {
        int u = i * 256 + tid;
        int row = u >> 4, c8 = u & 15;
        int m = bm * 128 + row;
        int srow = m & 2047, b = m >> 11;
        uint4 vv = *(const uint4*)&Ct[row * 136 + c8 * 8];
        *(uint4*)&qb[(((long)(b * 16 + h0 + (c8 >> 3))) * 2048 + srow) * 64 +
                     (c8 & 7) * 8] = vv;
      }
    } else if (g == 1) {
      for (int i = 0; i < 8; ++i) {
        int u = i * 256 + tid;
        int head = u >> 10, off = u & 1023;
        int jrel = off >> 9, kc = (off >> 8) & 1, t = (off >> 6) & 3;
        int quadK = (off >> 4) & 3, lcA = off & 15;
        int srl = jrel * 64 + t * 16 + lcA;
        uint4 vv = *(const uint4*)&Ct[srl * 136 + head * 64 + kc * 32 + quadK * 8];
        int m = bm * 128 + srl;
        int srow = m & 2047, b = m >> 11;
        int bh = b * 16 + h0 + head;
        int chunk = (srow >> 6) * 8 + kc * 4 + t;
        *(uint4*)&kb[(long)bh * 131072 + chunk * 512 + (quadK * 16 + lcA) * 8] = vv;
      }
    } else {
      for (int i = 0; i < 8; ++i) {
        int u = i * 256 + tid;
        int head = u >> 10, off = u & 1023;
        int jrel = off >> 9, kcV = (off >> 8) & 1, mt = (off >> 6) & 3;
        int quadV = (off >> 4) & 3, lcA = off & 15;
        int srl = jrel * 64 + kcV * 32 + quadV * 8;
        int d = mt * 16 + lcA;
        uint4 vv = *(const uint4*)&Ct[(head * 64 + d) * 136 + srl];
        int m = bm * 128 + srl;
        int srow = m & 2047, b = m >> 11;
        int bh = b * 16 + h0 + head;
        int chunk = (srow >> 6) * 8 + kcV * 4 + mt;
        *(uint4*)&vb[(long)bh * 131072 + chunk * 512 + (quadV * 16 + lcA) * 8] = vv;
      }
    }
  }
}

// ------------------------------------------------- projection GEMM (NT)
// C[4096 x 1024] fp32 = AO[4096 x 1024] frag * Wo[1024 x 1024]^T frag.
// ONE WAVE PER BLOCK, 64x64 tile, grid 1024, reg-streaming, XCD swizzle
// (8 bm x all 16 bn per XCD -> 1MB A + 2MB B), LDS-transposed fp32 epilogue.
__global__ __launch_bounds__(64) void gemm_proj(
    const ushort* __restrict__ A, const ushort* __restrict__ B,
    float* __restrict__ Cout) {
  __shared__ __align__(16) float T[64 * 68];
  const int lane = threadIdx.x, quad = lane >> 4, lc = lane & 15;
  const int bid = blockIdx.x;  // 1024 = 8 XCD-regions x 128
  const int r = bid >> 3;
  const int bm = (bid & 7) * 8 + (r >> 4);  // 8 bm per XCD
  const int bn = r & 15;

  f32x4 acc[4][4] = {};

  const ushort* Ap = A + (long)(bm * 4) * 16384 + lane * 8;
  const ushort* Bp = B + (long)(bn * 4) * 16384 + lane * 8;

#define GLD(AF, BF, K32)                                                       \
  {                                                                            \
    for (int t = 0; t < 4; ++t)                                                \
      AF[t] = *(const bf16x8*)&Ap[(long)t * 16384 + (K32) * 512];              \
    for (int t = 0; t < 4; ++t)                                                \
      BF[t] = *(const bf16x8*)&Bp[(long)t * 16384 + (K32) * 512];              \
  }
#define MM(AF, BF)                                                             \
  for (int rt = 0; rt < 4; ++rt)                                               \
    for (int ct = 0; ct < 4; ++ct)                                             \
      acc[rt][ct] = __builtin_amdgcn_mfma_f32_16x16x32_bf16(                   \
          AF[rt], BF[ct], acc[rt][ct], 0, 0, 0);

  bf16x8 a0[4], b0[4], a1[4], b1[4];
  GLD(a0, b0, 0);
  for (int k = 0; k < 32; k += 2) {
    GLD(a1, b1, k + 1);
    MM(a0, b0);
    int kn = (k + 2 < 32) ? k + 2 : 31;
    GLD(a0, b0, kn);
    MM(a1, b1);
  }
#undef GLD
#undef MM

  // transpose via LDS (single wave: DS pipe is in-order, CBAR suffices)
  for (int rt = 0; rt < 4; ++rt)
    for (int ct = 0; ct < 4; ++ct)
      for (int r2 = 0; r2 < 4; ++r2)
        T[(rt * 16 + quad * 4 + r2) * 68 + ct * 16 + lc] = acc[rt][ct][r2];
  CBAR();
  for (int p = 0; p < 16; ++p) {
    int row = p * 4 + quad;  // 4 rows per pass, 16 lanes x 16B = 256B/row
    float4 v = *(const float4*)&T[row * 68 + lc * 4];
    *(float4*)&Cout[(long)(bm * 64 + row) * 1024 + bn * 64 + lc * 4] = v;
  }
}

// ---------------------------------------------------------------- attention
// ONE WAVE PER BLOCK, 32 q-rows. Fragment-major coalesced K/V loads (r21),
// fixed-max softmax (bias dropped), 2x-unrolled A/B register ping-pong,
// setprio around MFMA clusters. Output stored FRAGMENT-MAJOR (feeds proj).
__global__ __launch_bounds__(64) void attn_kernel(
    const ushort* __restrict__ qb, const ushort* __restrict__ kb,
    const ushort* __restrict__ vt, ushort* __restrict__ out) {
  __shared__ __align__(16) ushort Psw2[2][32 * 64];
  const int lane = threadIdx.x;
  const int quad = lane >> 4, lc = lane & 15, l7 = lc & 7;
  const int bid = blockIdx.x;                   // 0..2047
  const int s = 63 - (bid >> 5);                // strip, big-work first
  const int bh = bid & 31;                      // bh ≡ bid (mod 8) -> XCD-local
  const int bidx = bh >> 4, h = bh & 15;
  const int qtbase = s * 32;

  bf16x8 qf[2][2];
  for (int kc = 0; kc < 2; ++kc)
    for (int q2 = 0; q2 < 2; ++q2)
      qf[kc][q2] = *(const bf16x8*)&qb[((long)bh * 2048 + qtbase + q2 * 16 + lc) * 64 +
                                       kc * 32 + quad * 8];

  f32x4 oacc[4][2] = {};
  float l_lane[2] = {0.0f, 0.0f};

  const ushort* K = kb + (long)bh * 131072;
  const ushort* Vt = vt + (long)bh * 131072;
  const int jmax = s >> 1;
  const int rowoff = (s & 1) * 32;
  const int lane8 = lane * 8;

#define LOADTILE(KF, VF, JT)                                                   \
  {                                                                            \
    const ushort* Kp_ = K + (JT) * 4096 + lane8;                               \
    const ushort* Vp_ = Vt + (JT) * 4096 + lane8;                              \
    for (int kc = 0; kc < 2; ++kc)                                             \
      for (int t = 0; t < 4; ++t) {                                            \
        KF[kc][t] = *(const bf16x8*)&Kp_[(kc * 4 + t) * 512];                  \
        VF[kc][t] = *(const bf16x8*)&Vp_[(kc * 4 + t) * 512];                  \
      }                                                                        \
  }

#define COMPUTE(KF, VF, J, PAR)                                                \
  {                                                                            \
    f32x4 sacc[4][2] = {};                                                     \
    __builtin_amdgcn_s_setprio(1);                                             \
    for (int kc = 0; kc < 2; ++kc)                                             \
      for (int kt = 0; kt < 4; ++kt)                                           \
        for (int q2 = 0; q2 < 2; ++q2)                                         \
          sacc[kt][q2] = __builtin_amdgcn_mfma_f32_16x16x32_bf16(              \
              KF[kc][kt], qf[kc][q2], sacc[kt][q2], 0, 0, 0);                  \
    __builtin_amdgcn_s_setprio(0);                                             \
    if ((J) == jmax) { /* causal partial tile */                               \
      for (int kt = 0; kt < 4; ++kt)                                           \
        for (int q2 = 0; q2 < 2; ++q2) {                                       \
          int rowrel = rowoff + q2 * 16 + lc;                                  \
          for (int r = 0; r < 4; ++r)                                          \
            if (kt * 16 + quad * 4 + r > rowrel) sacc[kt][q2][r] = -1.0e30f;   \
        }                                                                      \
    }                                                                          \
    ushort* Psw = Psw2[PAR];                                                   \
    for (int q2 = 0; q2 < 2; ++q2) {                                           \
      float p[4][4];                                                           \
      float rs = 0.0f;                                                         \
      for (int kt = 0; kt < 4; ++kt)                                           \
        for (int r = 0; r < 4; ++r) {                                          \
          p[kt][r] = fexp2(sacc[kt][q2][r]);                                   \
          rs += p[kt][r];                                                      \
        }                                                                      \
      l_lane[q2] += rs;                                                        \
      for (int kt = 0; kt < 4; ++kt) {                                         \
        uint2 pk = {pack2t(p[kt][0], p[kt][1]), pack2t(p[kt][2], p[kt][3])};   \
        *(uint2*)&Psw[(q2 * 16 + lc) * 64 +                                    \
                      (((kt * 2 + (quad >> 1)) ^ l7) << 3) +                   \
                      ((quad & 1) << 2)] = pk;                                 \
      }                                                                        \
    }                                                                          \
    CBAR(); /* compiler-only: P writes before P reads (HW DS in-order) */      \
    __builtin_amdgcn_s_setprio(1);                                             \
    for (int kc = 0; kc < 2; ++kc) {                                           \
      bf16x8 pf[2];                                                            \
      for (int q2 = 0; q2 < 2; ++q2)                                           \
        pf[q2] = *(const bf16x8*)&Psw[(q2 * 16 + lc) * 64 +                    \
                                      (((kc * 4 + quad) ^ l7) << 3)];          \
      for (int mt = 0; mt < 4; ++mt)                                           \
        for (int q2 = 0; q2 < 2; ++q2)                                         \
          oacc[mt][q2] = __builtin_amdgcn_mfma_f32_16x16x32_bf16(              \
              VF[kc][mt], pf[q2], oacc[mt][q2], 0, 0, 0);                      \
    }                                                                          \
    __builtin_amdgcn_s_setprio(0);                                             \
  }

  // 2x-unrolled software pipeline with A/B register ping-pong.
  bf16x8 kA[2][4], vA[2][4], kB[2][4], vB[2][4];
  LOADTILE(kA, vA, 0);
  int j = 0;
  while (true) {
    int jn = (j < jmax) ? j + 1 : j;
    LOADTILE(kB, vB, jn);
    COMPUTE(kA, vA, j, 0);
    if (j >= jmax) break;
    ++j;
    int jn2 = (j < jmax) ? j + 1 : j;
    LOADTILE(kA, vA, jn2);
    COMPUTE(kB, vB, j, 1);
    if (j >= jmax) break;
    ++j;
  }
#undef LOADTILE
#undef COMPUTE

  // epilogue: reduce l across quads, normalize, store via LDS
  float l_[2];
  for (int q2 = 0; q2 < 2; ++q2) {
    float rs = l_lane[q2];
    rs += __shfl_xor(rs, 16, 64);
    rs += __shfl_xor(rs, 32, 64);
    l_[q2] = rs;
  }
  ushort* Psw = Psw2[0];
  CBAR();
  for (int q2 = 0; q2 < 2; ++q2) {
    float linv = 1.0f / l_[q2];
    for (int mt = 0; mt < 4; ++mt) {
      uint2 pk = {pack2(oacc[mt][q2][0] * linv, oacc[mt][q2][1] * linv),
                  pack2(oacc[mt][q2][2] * linv, oacc[mt][q2][3] * linv)};
      *(uint2*)&Psw[(q2 * 16 + lc) * 64 + (((mt * 2 + (quad >> 1)) ^ l7) << 3) +
                    ((quad & 1) << 2)] = pk;
    }
  }
  CBAR();
  {
    // store FRAGMENT-MAJOR: AO[m][col] -> chunk (m>>4, col>>5), elem
    // (((col>>3)&3)*16 + (m&15))*8. col = h*64 + c8*8.
    int r2 = lane >> 1;
    long m = (long)bidx * 2048 + qtbase + r2;
    int m4 = (int)(m >> 4), rr = (int)(m & 15);
    for (int c = 0; c < 4; ++c) {
      int c8 = (lane & 1) * 4 + c;
      uint4 vv = *(const uint4*)&Psw[r2 * 64 + ((c8 ^ (r2 & 7)) << 3)];
      *(uint4*)&out[((long)m4 * 32 + h * 2 + (c8 >> 2)) * 512 +
                    ((c8 & 3) * 16 + rr) * 8] = vv;
    }
  }
}

extern "C" void kernel_launch(void* const* d_in, const int* in_sizes, int n_in,
                              void* d_out, int out_size, void* d_ws, size_t ws_size,
                              hipStream_t stream) {
  const float* x = nullptr;     // 4194304 elems
  const float* Wqkv = nullptr;  // 3145728 elems
  const float* Wo = nullptr;    // 1048576 elems
  for (int i = 0; i < n_in; ++i) {
    if (in_sizes[i] == 4194304) x = (const float*)d_in[i];
    else if (in_sizes[i] == 3145728) Wqkv = (const float*)d_in[i];
    else if (in_sizes[i] == 1048576) Wo = (const float*)d_in[i];
  }
  float* out = (float*)d_out;  // [4096,1024] fp32 (16 MiB)

  // Workspace (32 MiB) timeline:
  //  [0,8)   qbuf (Q row-major)          -> later Wo bf16 frag (woh)
  //  [8,16)  kbuf (K fragment-major)
  //  [16,24) vbuf (V fragment-major)
  //  [24,32) scratch: Wqkv bf16 frag -> attn output frag (ao) after gemm1
  ushort* qbuf = (ushort*)d_ws;
  ushort* kbuf = qbuf + 4194304;
  ushort* vbuf = kbuf + 4194304;
  ushort* scr4 = vbuf + 4194304;
  ushort* wqkvh = scr4;                // Wqkv bf16 frag [24..30)
  ushort* ao   = scr4;                 // attn out frag (after gemm1 done with B)
  ushort* woh  = qbuf;                 // Wo bf16 frag (after attn done with Q)
  ushort* xh   = (ushort*)d_out;       // x bf16 frag in d_out scratch

  conv_frag2<<<3584, 256, 0, stream>>>(x, xh, 2048, Wqkv, wqkvh);
  gemm_bt<<<768, 256, 0, stream>>>(xh, wqkvh, qbuf, kbuf, vbuf);
  attn_kernel<<<2048, 64, 0, stream>>>(qbuf, kbuf, vbuf, ao);
  conv_frag<<<512, 256, 0, stream>>>(Wo, woh);
  gemm_proj<<<1024, 64, 0, stream>>>(ao, woh, out);
}